// Round 20
// baseline (40.048 us; speedup 1.0000x reference)
//
#include <hip/hip_runtime.h>

#define B_SZ   256
#define T_SZ   512
#define EMB    128
#define HID    256
#define NCLS   32000

typedef __attribute__((ext_vector_type(8))) short short8;
typedef __attribute__((ext_vector_type(4))) float f32x4;

__device__ inline unsigned short bf16rne(float f) {
    union { float f; unsigned int u; } v; v.f = f;
    unsigned int u = v.u;
    u += 0x7FFFu + ((u >> 16) & 1u);
    return (unsigned short)(u >> 16);
}
__device__ inline unsigned pkhi(float lo, float hi) {
    union { float f; unsigned u; } a, b;
    a.f = lo; b.f = hi;
    return ((b.u + 0x8000u) & 0xFFFF0000u) | ((a.u + 0x8000u) >> 16);
}

// ---------------------------------------------------------------------------
// INSTRUMENTATION ROUND (pre-declared in R19): kernels are BYTE-IDENTICAL
// to R19; kernel_launch launches lstm 3x then logits 1x. lstm is idempotent
// (same inputs -> same hws contents), so output is unchanged.
// Algebra: R20_total - R19_total = 2 * (lstm + gap).
//   Delta ~8-12  -> logits ~22-24us is the pig (attack logits next)
//   Delta ~36-40 -> lstm ~19us confirmed (attack its shared invariant)
//   Delta ~20-25 -> both ~10us (attack the dispatch gap)
// ---------------------------------------------------------------------------

__global__ __launch_bounds__(512, 2)
void lstm_h_last(const int* __restrict__ X, const float* __restrict__ C_table,
                 const float* __restrict__ U_i, const float* __restrict__ b_i,
                 const float* __restrict__ U_c, const float* __restrict__ b_c,
                 const float* __restrict__ U_o, const float* __restrict__ b_o,
                 unsigned short* __restrict__ hws) {
    __shared__ float e[2][EMB];
    __shared__ int   tok[2];
    __shared__ f32x4 part[8][3][2][64];      // 48 KB

    const int t    = threadIdx.x;            // 0..511
    const int wid  = t >> 6;                 // 0..7 = e-group
    const int lane = t & 63;                 // k-quad
    const int m0   = blockIdx.x * 2;
    const int kb   = lane * 4;

    if (t < 2) tok[t] = X[(size_t)(m0 + t) * T_SZ + (T_SZ - 1)];
    __syncthreads();
    if (t < 256) e[t >> 7][t & 127] =
        C_table[(size_t)tok[t >> 7] * EMB + (t & 127)];
    __syncthreads();

    f32x4 acc[3][2] = {};                    // [gate][row]
    #pragma unroll 4
    for (int j = 0; j < 16; ++j) {
        const int ee = wid * 16 + j;
        const f32x4 ui = *reinterpret_cast<const f32x4*>(U_i + (size_t)ee * HID + kb);
        const f32x4 uc = *reinterpret_cast<const f32x4*>(U_c + (size_t)ee * HID + kb);
        const f32x4 uo = *reinterpret_cast<const f32x4*>(U_o + (size_t)ee * HID + kb);
        #pragma unroll
        for (int r = 0; r < 2; ++r) {
            const float ev = e[r][ee];       // LDS broadcast
            acc[0][r] += ev * ui;
            acc[1][r] += ev * uc;
            acc[2][r] += ev * uo;
        }
    }
    #pragma unroll
    for (int g = 0; g < 3; ++g)
        #pragma unroll
        for (int r = 0; r < 2; ++r)
            part[wid][g][r][lane] = acc[g][r];
    __syncthreads();

    if (t < 128) {                           // waves 0-1: reduce + activate
        const int r = wid;                   // 0..1
        const int m = m0 + r;
        f32x4 s[3];
        #pragma unroll
        for (int g = 0; g < 3; ++g) {
            s[g] = part[0][g][r][lane];
            #pragma unroll
            for (int w = 1; w < 8; ++w) s[g] += part[w][g][r][lane];
        }
        const f32x4 bi = *reinterpret_cast<const f32x4*>(b_i + kb);
        const f32x4 bc = *reinterpret_cast<const f32x4*>(b_c + kb);
        const f32x4 bo = *reinterpret_cast<const f32x4*>(b_o + kb);
        float h[4];
        #pragma unroll
        for (int c = 0; c < 4; ++c) {
            const float i0 = 1.f / (1.f + expf(-(s[0][c] + bi[c])));
            const float g0 = tanhf(s[1][c] + bc[c]);
            const float o0 = 1.f / (1.f + expf(-(s[2][c] + bo[c])));
            h[c] = o0 * tanhf(i0 * g0);
        }
        const int frag = (m >> 4) * 8 + (lane >> 3);
        const int li   = ((lane >> 1) & 3) * 16 + (m & 15);
        unsigned* dst = reinterpret_cast<unsigned*>(
            hws + frag * 512 + li * 8 + (lane & 1) * 4);
        dst[0] = pkhi(h[0], h[1]);
        dst[1] = pkhi(h[2], h[3]);
    }
}

__global__ __launch_bounds__(512, 2)
void logits_gemm(const unsigned short* __restrict__ hws,
                 const float* __restrict__ Ww,
                 const float* __restrict__ b_out,
                 float* __restrict__ out) {
    __shared__ unsigned short Hs[B_SZ * HID];   // 128 KB, frag-major linear

    const int t    = threadIdx.x;        // 0..511
    const int wid  = t >> 6;             // 0..7
    const int lane = t & 63;
    const int l15  = lane & 15;
    const int lq   = lane >> 4;          // 0..3

    const int nbase = blockIdx.x * 128 + wid * 16;

    const float* wrow = Ww + (size_t)(nbase + l15) * HID + lq * 8;
    f32x4 wf[16];
    #pragma unroll
    for (int ks = 0; ks < 8; ++ks) {
        wf[2 * ks]     = *reinterpret_cast<const f32x4*>(wrow + ks * 32);
        wf[2 * ks + 1] = *reinterpret_cast<const f32x4*>(wrow + ks * 32 + 4);
    }

    #pragma unroll
    for (int j = 0; j < 16; ++j) {
        const unsigned short* src = hws + (wid * 16 + j) * 512;
        __builtin_amdgcn_global_load_lds(
            (const __attribute__((address_space(1))) unsigned int*)(src + lane * 8),
            (__attribute__((address_space(3))) unsigned int*)(Hs + (wid * 16 + j) * 512),
            16, 0, 0);
    }

    #pragma unroll
    for (int i = 0; i < 16; ++i) asm volatile("" : "+v"(wf[i]));
    asm volatile("s_waitcnt vmcnt(0)" ::: "memory");
    __builtin_amdgcn_s_barrier();
    __builtin_amdgcn_sched_barrier(0);

    short8 aw[8];
    #pragma unroll
    for (int ks = 0; ks < 8; ++ks) {
        union { short8 s; unsigned u[4]; } p;
        p.u[0] = pkhi(wf[2 * ks][0],     wf[2 * ks][1]);
        p.u[1] = pkhi(wf[2 * ks][2],     wf[2 * ks][3]);
        p.u[2] = pkhi(wf[2 * ks + 1][0], wf[2 * ks + 1][1]);
        p.u[3] = pkhi(wf[2 * ks + 1][2], wf[2 * ks + 1][3]);
        aw[ks] = p.s;
    }

    f32x4 bv = *reinterpret_cast<const f32x4*>(b_out + nbase + lq * 4);

    const unsigned short* hbase = Hs + lane * 8;
    f32x4 acc[16] = {};
    #pragma unroll
    for (int ks = 0; ks < 8; ++ks) {
        #pragma unroll
        for (int mf = 0; mf < 16; ++mf) {
            short8 bh = *reinterpret_cast<const short8*>(
                hbase + (mf * 8 + ks) * 512);
            acc[mf] = __builtin_amdgcn_mfma_f32_16x16x32_bf16(
                aw[ks], bh, acc[mf], 0, 0, 0);
        }
    }

    #pragma unroll
    for (int mf = 0; mf < 16; ++mf) {
        f32x4 o = acc[mf] + bv;
        *reinterpret_cast<f32x4*>(
            out + (size_t)(mf * 16 + l15) * NCLS + nbase + lq * 4) = o;
    }
}

// ---------------------------------------------------------------------------
extern "C" void kernel_launch(void* const* d_in, const int* in_sizes, int n_in,
                              void* d_out, int out_size, void* d_ws, size_t ws_size,
                              hipStream_t stream) {
    const int*   X       = (const int*)  d_in[0];
    const float* C_table = (const float*)d_in[1];
    const float* U_i     = (const float*)d_in[2];
    const float* b_i     = (const float*)d_in[4];
    const float* U_c     = (const float*)d_in[8];
    const float* b_c     = (const float*)d_in[10];
    const float* U_o     = (const float*)d_in[11];
    const float* b_o     = (const float*)d_in[13];
    const float* W_w     = (const float*)d_in[26];
    const float* b_out   = (const float*)d_in[27];
    float* out = (float*)d_out;

    unsigned short* hws = (unsigned short*)d_ws;  // bf16 h_last, frag-major

    // INSTRUMENTATION: lstm x3 (idempotent) -> Delta vs R19 = 2*(lstm+gap)
    lstm_h_last<<<B_SZ / 2, 512, 0, stream>>>(X, C_table, U_i, b_i, U_c, b_c,
                                              U_o, b_o, hws);
    lstm_h_last<<<B_SZ / 2, 512, 0, stream>>>(X, C_table, U_i, b_i, U_c, b_c,
                                              U_o, b_o, hws);
    lstm_h_last<<<B_SZ / 2, 512, 0, stream>>>(X, C_table, U_i, b_i, U_c, b_c,
                                              U_o, b_o, hws);
    logits_gemm<<<NCLS / 128, 512, 0, stream>>>(hws, W_w, b_out, out);
}

// Round 21
// 37.243 us; speedup vs baseline: 1.0753x; 1.0753x over previous
//
#include <hip/hip_runtime.h>

#define B_SZ   256
#define T_SZ   512
#define EMB    128
#define HID    256
#define NCLS   32000

typedef __attribute__((ext_vector_type(8))) short short8;
typedef __attribute__((ext_vector_type(4))) float f32x4;

__device__ inline unsigned short bf16rne(float f) {
    union { float f; unsigned int u; } v; v.f = f;
    unsigned int u = v.u;
    u += 0x7FFFu + ((u >> 16) & 1u);
    return (unsigned short)(u >> 16);
}
__device__ inline unsigned pkhi(float lo, float hi) {
    union { float f; unsigned u; } a, b;
    a.f = lo; b.f = hi;
    return ((b.u + 0x8000u) & 0xFFFF0000u) | ((a.u + 0x8000u) >> 16);
}

// ---------------------------------------------------------------------------
// h is FRAG-MAJOR in d_ws: (m,k) -> frag=(m>>4)*8+(k>>5),
// lane=((k>>3)&3)*16+(m&15), idx=frag*512+lane*8+(k&7).
// Each B-fragment = contiguous lane-linear 1 KB -> linear gload_lds staging
// (rule 21) and conflict-free ds_read_b128 (R7-proven).
// ---------------------------------------------------------------------------

// ---------------------------------------------------------------------------
// Kernel 1: VERBATIM R19 lstm (R20 instrumentation: lstm+gap = 5.75 us —
// this kernel is NOT the bottleneck; do not touch it again).
// ---------------------------------------------------------------------------
__global__ __launch_bounds__(512, 2)
void lstm_h_last(const int* __restrict__ X, const float* __restrict__ C_table,
                 const float* __restrict__ U_i, const float* __restrict__ b_i,
                 const float* __restrict__ U_c, const float* __restrict__ b_c,
                 const float* __restrict__ U_o, const float* __restrict__ b_o,
                 unsigned short* __restrict__ hws) {
    __shared__ float e[2][EMB];
    __shared__ int   tok[2];
    __shared__ f32x4 part[8][3][2][64];      // 48 KB

    const int t    = threadIdx.x;            // 0..511
    const int wid  = t >> 6;                 // 0..7 = e-group
    const int lane = t & 63;                 // k-quad
    const int m0   = blockIdx.x * 2;
    const int kb   = lane * 4;

    if (t < 2) tok[t] = X[(size_t)(m0 + t) * T_SZ + (T_SZ - 1)];
    __syncthreads();
    if (t < 256) e[t >> 7][t & 127] =
        C_table[(size_t)tok[t >> 7] * EMB + (t & 127)];
    __syncthreads();

    f32x4 acc[3][2] = {};                    // [gate][row]
    #pragma unroll 4
    for (int j = 0; j < 16; ++j) {
        const int ee = wid * 16 + j;
        const f32x4 ui = *reinterpret_cast<const f32x4*>(U_i + (size_t)ee * HID + kb);
        const f32x4 uc = *reinterpret_cast<const f32x4*>(U_c + (size_t)ee * HID + kb);
        const f32x4 uo = *reinterpret_cast<const f32x4*>(U_o + (size_t)ee * HID + kb);
        #pragma unroll
        for (int r = 0; r < 2; ++r) {
            const float ev = e[r][ee];
            acc[0][r] += ev * ui;
            acc[1][r] += ev * uc;
            acc[2][r] += ev * uo;
        }
    }
    #pragma unroll
    for (int g = 0; g < 3; ++g)
        #pragma unroll
        for (int r = 0; r < 2; ++r)
            part[wid][g][r][lane] = acc[g][r];
    __syncthreads();

    if (t < 128) {
        const int r = wid;
        const int m = m0 + r;
        f32x4 s[3];
        #pragma unroll
        for (int g = 0; g < 3; ++g) {
            s[g] = part[0][g][r][lane];
            #pragma unroll
            for (int w = 1; w < 8; ++w) s[g] += part[w][g][r][lane];
        }
        const f32x4 bi = *reinterpret_cast<const f32x4*>(b_i + kb);
        const f32x4 bc = *reinterpret_cast<const f32x4*>(b_c + kb);
        const f32x4 bo = *reinterpret_cast<const f32x4*>(b_o + kb);
        float h[4];
        #pragma unroll
        for (int c = 0; c < 4; ++c) {
            const float i0 = 1.f / (1.f + expf(-(s[0][c] + bi[c])));
            const float g0 = tanhf(s[1][c] + bc[c]);
            const float o0 = 1.f / (1.f + expf(-(s[2][c] + bo[c])));
            h[c] = o0 * tanhf(i0 * g0);
        }
        const int frag = (m >> 4) * 8 + (lane >> 3);
        const int li   = ((lane >> 1) & 3) * 16 + (m & 15);
        unsigned* dst = reinterpret_cast<unsigned*>(
            hws + frag * 512 + li * 8 + (lane & 1) * 4);
        dst[0] = pkhi(h[0], h[1]);
        dst[1] = pkhi(h[2], h[3]);
    }
}

// ---------------------------------------------------------------------------
// Kernel 2 (R21 change): PERSISTENT 2-TILE PIPELINE with counted vmcnt.
// R20 instrumentation: one-shot logits = 22.8 us vs ~10.5 floor — the gap
// is phase serialization (read-wait 6us -> compute -> 5us store drain,
// never overlapped). Now each block owns 256 n (two 128-n tiles):
//   issue bias(2) + h(16 gload_lds) + W0(16) + W1(16)   [vmcnt 50]
//   wait vmcnt(16)  -> bias+h+W0 landed (W1 in flight); s_barrier
//   cvt W0, MFMA t0, store t0 (+16 st -> 32 outstanding)
//   wait vmcnt(16)  -> W1 landed, t0 STORES STILL IN FLIGHT (the overlap)
//   cvt W1, MFMA t1, store t1; end-of-kernel drains.
// h staged ONCE for both tiles. Grid 125 x 512thr (125 CUs x 2x data;
// 256KB outstanding/CU >> 48KB latency-BW product -> HBM stays saturated).
// Peak ~165 VGPR < 256 cap at (512,2). Counted-vmcnt + raw s_barrier per
// m201 precedent (compiler does not force vmcnt(0) at raw barriers).
// ---------------------------------------------------------------------------
__global__ __launch_bounds__(512, 2)
void logits_gemm(const unsigned short* __restrict__ hws,
                 const float* __restrict__ Ww,
                 const float* __restrict__ b_out,
                 float* __restrict__ out) {
    __shared__ unsigned short Hs[B_SZ * HID];   // 128 KB, frag-major linear

    const int t    = threadIdx.x;        // 0..511
    const int wid  = t >> 6;             // 0..7
    const int lane = t & 63;
    const int l15  = lane & 15;
    const int lq   = lane >> 4;          // 0..3

    const int nb0 = blockIdx.x * 256 + wid * 16;          // tile0 stripe
    const int nb1 = nb0 + 128;                            // tile1 stripe

    // ---- bias first (oldest in vmcnt ledger) ----
    f32x4 bv0 = *reinterpret_cast<const f32x4*>(b_out + nb0 + lq * 4);
    f32x4 bv1 = *reinterpret_cast<const f32x4*>(b_out + nb1 + lq * 4);

    // ---- h staging: 16 x gload_lds (this wave's 16 KB slice) ----
    #pragma unroll
    for (int j = 0; j < 16; ++j) {
        const unsigned short* src = hws + (wid * 16 + j) * 512;
        __builtin_amdgcn_global_load_lds(
            (const __attribute__((address_space(1))) unsigned int*)(src + lane * 8),
            (__attribute__((address_space(3))) unsigned int*)(Hs + (wid * 16 + j) * 512),
            16, 0, 0);
    }

    // ---- W tile0 then tile1: 16+16 dwordx4 direct to regs ----
    const float* wrow0 = Ww + (size_t)(nb0 + l15) * HID + lq * 8;
    const float* wrow1 = Ww + (size_t)(nb1 + l15) * HID + lq * 8;
    f32x4 wf0[16], wf1[16];
    #pragma unroll
    for (int ks = 0; ks < 8; ++ks) {
        wf0[2 * ks]     = *reinterpret_cast<const f32x4*>(wrow0 + ks * 32);
        wf0[2 * ks + 1] = *reinterpret_cast<const f32x4*>(wrow0 + ks * 32 + 4);
    }
    #pragma unroll
    for (int ks = 0; ks < 8; ++ks) {
        wf1[2 * ks]     = *reinterpret_cast<const f32x4*>(wrow1 + ks * 32);
        wf1[2 * ks + 1] = *reinterpret_cast<const f32x4*>(wrow1 + ks * 32 + 4);
    }

    // ---- pin everything so issue order == source order ----
    asm volatile("" : "+v"(bv0), "+v"(bv1));
    #pragma unroll
    for (int i = 0; i < 16; ++i) asm volatile("" : "+v"(wf0[i]), "+v"(wf1[i]));
    __builtin_amdgcn_sched_barrier(0);

    // ---- wait: bias + h + W0 landed (oldest 34 of 50); W1 in flight ----
    asm volatile("s_waitcnt vmcnt(16)" ::: "memory");
    __builtin_amdgcn_s_barrier();                 // all waves' h in LDS
    __builtin_amdgcn_sched_barrier(0);

    // ---- tile0: cvt, MFMA, store ----
    short8 aw[8];
    #pragma unroll
    for (int ks = 0; ks < 8; ++ks) {
        union { short8 s; unsigned u[4]; } p;
        p.u[0] = pkhi(wf0[2 * ks][0],     wf0[2 * ks][1]);
        p.u[1] = pkhi(wf0[2 * ks][2],     wf0[2 * ks][3]);
        p.u[2] = pkhi(wf0[2 * ks + 1][0], wf0[2 * ks + 1][1]);
        p.u[3] = pkhi(wf0[2 * ks + 1][2], wf0[2 * ks + 1][3]);
        aw[ks] = p.s;
    }
    const unsigned short* hbase = Hs + lane * 8;
    {
        f32x4 acc[16] = {};
        #pragma unroll
        for (int ks = 0; ks < 8; ++ks)
            #pragma unroll
            for (int mf = 0; mf < 16; ++mf) {
                short8 bh = *reinterpret_cast<const short8*>(
                    hbase + (mf * 8 + ks) * 512);
                acc[mf] = __builtin_amdgcn_mfma_f32_16x16x32_bf16(
                    aw[ks], bh, acc[mf], 0, 0, 0);
            }
        #pragma unroll
        for (int mf = 0; mf < 16; ++mf) {
            f32x4 o = acc[mf] + bv0;
            *reinterpret_cast<f32x4*>(
                out + (size_t)(mf * 16 + l15) * NCLS + nb0 + lq * 4) = o;
        }
    }
    __builtin_amdgcn_sched_barrier(0);

    // ---- wait: W1 landed (oldest 16 of 32); tile0 stores STILL flying ----
    asm volatile("s_waitcnt vmcnt(16)" ::: "memory");
    __builtin_amdgcn_sched_barrier(0);

    // ---- tile1: cvt, MFMA, store (end-of-kernel drains stores) ----
    #pragma unroll
    for (int ks = 0; ks < 8; ++ks) {
        union { short8 s; unsigned u[4]; } p;
        p.u[0] = pkhi(wf1[2 * ks][0],     wf1[2 * ks][1]);
        p.u[1] = pkhi(wf1[2 * ks][2],     wf1[2 * ks][3]);
        p.u[2] = pkhi(wf1[2 * ks + 1][0], wf1[2 * ks + 1][1]);
        p.u[3] = pkhi(wf1[2 * ks + 1][2], wf1[2 * ks + 1][3]);
        aw[ks] = p.s;
    }
    {
        f32x4 acc[16] = {};
        #pragma unroll
        for (int ks = 0; ks < 8; ++ks)
            #pragma unroll
            for (int mf = 0; mf < 16; ++mf) {
                short8 bh = *reinterpret_cast<const short8*>(
                    hbase + (mf * 8 + ks) * 512);
                acc[mf] = __builtin_amdgcn_mfma_f32_16x16x32_bf16(
                    aw[ks], bh, acc[mf], 0, 0, 0);
            }
        #pragma unroll
        for (int mf = 0; mf < 16; ++mf) {
            f32x4 o = acc[mf] + bv1;
            *reinterpret_cast<f32x4*>(
                out + (size_t)(mf * 16 + l15) * NCLS + nb1 + lq * 4) = o;
        }
    }
}

// ---------------------------------------------------------------------------
extern "C" void kernel_launch(void* const* d_in, const int* in_sizes, int n_in,
                              void* d_out, int out_size, void* d_ws, size_t ws_size,
                              hipStream_t stream) {
    const int*   X       = (const int*)  d_in[0];
    const float* C_table = (const float*)d_in[1];
    const float* U_i     = (const float*)d_in[2];
    const float* b_i     = (const float*)d_in[4];
    const float* U_c     = (const float*)d_in[8];
    const float* b_c     = (const float*)d_in[10];
    const float* U_o     = (const float*)d_in[11];
    const float* b_o     = (const float*)d_in[13];
    const float* W_w     = (const float*)d_in[26];
    const float* b_out   = (const float*)d_in[27];
    float* out = (float*)d_out;

    unsigned short* hws = (unsigned short*)d_ws;  // bf16 h_last, frag-major

    lstm_h_last<<<B_SZ / 2, 512, 0, stream>>>(X, C_table, U_i, b_i, U_c, b_c,
                                              U_o, b_o, hws);
    logits_gemm<<<NCLS / 256, 512, 0, stream>>>(hws, W_w, b_out, out);
}

// Round 22
// 31.245 us; speedup vs baseline: 1.2817x; 1.1920x over previous
//
#include <hip/hip_runtime.h>

#define B_SZ   256
#define T_SZ   512
#define EMB    128
#define HID    256
#define NCLS   32000

typedef __attribute__((ext_vector_type(8))) short short8;
typedef __attribute__((ext_vector_type(4))) float f32x4;

__device__ inline unsigned short bf16rne(float f) {
    union { float f; unsigned int u; } v; v.f = f;
    unsigned int u = v.u;
    u += 0x7FFFu + ((u >> 16) & 1u);
    return (unsigned short)(u >> 16);
}
__device__ inline unsigned pkhi(float lo, float hi) {
    union { float f; unsigned u; } a, b;
    a.f = lo; b.f = hi;
    return ((b.u + 0x8000u) & 0xFFFF0000u) | ((a.u + 0x8000u) >> 16);
}

// ---------------------------------------------------------------------------
// h is FRAG-MAJOR in d_ws: (m,k) -> frag=(m>>4)*8+(k>>5),
// lane=((k>>3)&3)*16+(m&15), idx=frag*512+lane*8+(k&7).
// Each fragment = contiguous lane-linear 1 KB -> logits reads it with ONE
// coalesced dwordx4 per fragment per lane (no LDS needed for h at all).
// ---------------------------------------------------------------------------

// ---------------------------------------------------------------------------
// Kernel 1: VERBATIM R19 lstm (R20 instrumentation: lstm+gap = 5.75 us).
// ---------------------------------------------------------------------------
__global__ __launch_bounds__(512, 2)
void lstm_h_last(const int* __restrict__ X, const float* __restrict__ C_table,
                 const float* __restrict__ U_i, const float* __restrict__ b_i,
                 const float* __restrict__ U_c, const float* __restrict__ b_c,
                 const float* __restrict__ U_o, const float* __restrict__ b_o,
                 unsigned short* __restrict__ hws) {
    __shared__ float e[2][EMB];
    __shared__ int   tok[2];
    __shared__ f32x4 part[8][3][2][64];      // 48 KB

    const int t    = threadIdx.x;            // 0..511
    const int wid  = t >> 6;                 // 0..7 = e-group
    const int lane = t & 63;                 // k-quad
    const int m0   = blockIdx.x * 2;
    const int kb   = lane * 4;

    if (t < 2) tok[t] = X[(size_t)(m0 + t) * T_SZ + (T_SZ - 1)];
    __syncthreads();
    if (t < 256) e[t >> 7][t & 127] =
        C_table[(size_t)tok[t >> 7] * EMB + (t & 127)];
    __syncthreads();

    f32x4 acc[3][2] = {};                    // [gate][row]
    #pragma unroll 4
    for (int j = 0; j < 16; ++j) {
        const int ee = wid * 16 + j;
        const f32x4 ui = *reinterpret_cast<const f32x4*>(U_i + (size_t)ee * HID + kb);
        const f32x4 uc = *reinterpret_cast<const f32x4*>(U_c + (size_t)ee * HID + kb);
        const f32x4 uo = *reinterpret_cast<const f32x4*>(U_o + (size_t)ee * HID + kb);
        #pragma unroll
        for (int r = 0; r < 2; ++r) {
            const float ev = e[r][ee];
            acc[0][r] += ev * ui;
            acc[1][r] += ev * uc;
            acc[2][r] += ev * uo;
        }
    }
    #pragma unroll
    for (int g = 0; g < 3; ++g)
        #pragma unroll
        for (int r = 0; r < 2; ++r)
            part[wid][g][r][lane] = acc[g][r];
    __syncthreads();

    if (t < 128) {
        const int r = wid;
        const int m = m0 + r;
        f32x4 s[3];
        #pragma unroll
        for (int g = 0; g < 3; ++g) {
            s[g] = part[0][g][r][lane];
            #pragma unroll
            for (int w = 1; w < 8; ++w) s[g] += part[w][g][r][lane];
        }
        const f32x4 bi = *reinterpret_cast<const f32x4*>(b_i + kb);
        const f32x4 bc = *reinterpret_cast<const f32x4*>(b_c + kb);
        const f32x4 bo = *reinterpret_cast<const f32x4*>(b_o + kb);
        float h[4];
        #pragma unroll
        for (int c = 0; c < 4; ++c) {
            const float i0 = 1.f / (1.f + expf(-(s[0][c] + bi[c])));
            const float g0 = tanhf(s[1][c] + bc[c]);
            const float o0 = 1.f / (1.f + expf(-(s[2][c] + bo[c])));
            h[c] = o0 * tanhf(i0 * g0);
        }
        const int frag = (m >> 4) * 8 + (lane >> 3);
        const int li   = ((lane >> 1) & 3) * 16 + (m & 15);
        unsigned* dst = reinterpret_cast<unsigned*>(
            hws + frag * 512 + li * 8 + (lane & 1) * 4);
        dst[0] = pkhi(h[0], h[1]);
        dst[1] = pkhi(h[2], h[3]);
    }
}

// ---------------------------------------------------------------------------
// Kernel 2 (R22 change): 64-n tile, h IN REGISTERS, W in 64 KB LDS ->
// 2 blocks/CU, 500 blocks (full chip — R21's 125-block pipeline starved
// half the fabric; R18's regression was W re-reads per m-half, fixed here:
// W read exactly once, all 256 m per block).
// Per wave (8 waves x 32 m each):
//   1. bh[16] = its 32-m h fragments, 16 coalesced dwordx4 (L2/L3), pinned
//   2. stage 8 W rows via global_load_lds, source pre-swizzled XOR(r&7)
//      (R9-verbatim; read-side same XOR -> ~2-way conflicts = free)
//   3. one vmcnt(0) + s_barrier
//   4. 4 n-subtiles: bias load (hidden under MFMA), pack aw from LDS,
//      16 MFMA, bias add, 2 f32x4 stores — stores spread through compute;
//      block B's load burst overlaps block A's compute/stores (m114).
// Peak ~123 VGPR < 128 cap at (512,2): no spill, true 2 blocks/CU.
// ---------------------------------------------------------------------------
__global__ __launch_bounds__(512, 2)
void logits_gemm(const unsigned short* __restrict__ hws,
                 const float* __restrict__ Ww,
                 const float* __restrict__ b_out,
                 float* __restrict__ out) {
    __shared__ float Wlds[64 * HID];     // 64 KB: the block's 64 W rows, f32

    const int t    = threadIdx.x;        // 0..511
    const int wid  = t >> 6;             // 0..7
    const int lane = t & 63;
    const int l15  = lane & 15;
    const int lq   = lane >> 4;          // 0..3

    const int n0 = blockIdx.x * 64;      // block's n-tile
    const int mw = wid * 32;             // wave's m-strip

    // ---- 1. bh: this wave's 32-m h fragments, direct to regs ----
    short8 bh[16];
    #pragma unroll
    for (int mf = 0; mf < 2; ++mf)
        #pragma unroll
        for (int ks = 0; ks < 8; ++ks) {
            const int f = ((mw >> 4) + mf) * 8 + ks;
            bh[mf * 8 + ks] = *reinterpret_cast<const short8*>(
                hws + f * 512 + lane * 8);
        }

    // ---- 2. stage W rows wid*8..wid*8+7 (source pre-swizzled) ----
    #pragma unroll
    for (int i = 0; i < 8; ++i) {
        const int r = wid * 8 + i;                       // wave-uniform
        const float* src = Ww + (size_t)(n0 + r) * HID + ((lane ^ (r & 7)) << 2);
        __builtin_amdgcn_global_load_lds(
            (const __attribute__((address_space(1))) unsigned int*)src,
            (__attribute__((address_space(3))) unsigned int*)(Wlds + r * HID),
            16, 0, 0);
    }

    // ---- 3. pin bh, drain, barrier ----
    #pragma unroll
    for (int i = 0; i < 16; ++i) asm volatile("" : "+v"(bh[i]));
    asm volatile("s_waitcnt vmcnt(0)" ::: "memory");
    __builtin_amdgcn_s_barrier();
    __builtin_amdgcn_sched_barrier(0);

    // ---- 4. 4 n-subtiles of 16 ----
    #pragma unroll
    for (int s = 0; s < 4; ++s) {
        // bias issued first; consumed only at store -> latency hidden
        f32x4 bv = *reinterpret_cast<const f32x4*>(b_out + n0 + s * 16 + lq * 4);

        // A-frags: W row R, read with the same XOR (2-way max, free)
        const int R  = s * 16 + l15;
        const int sw = R & 7;
        const float* rp = Wlds + R * HID;
        short8 aw[8];
        #pragma unroll
        for (int ks = 0; ks < 8; ++ks) {
            const int j0 = ks * 8 + lq * 2;              // 16B-unit index
            f32x4 a0 = *reinterpret_cast<const f32x4*>(rp + ((j0 ^ sw) << 2));
            f32x4 a1 = *reinterpret_cast<const f32x4*>(rp + (((j0 + 1) ^ sw) << 2));
            union { short8 v; unsigned u[4]; } p;
            p.u[0] = pkhi(a0[0], a0[1]);
            p.u[1] = pkhi(a0[2], a0[3]);
            p.u[2] = pkhi(a1[0], a1[1]);
            p.u[3] = pkhi(a1[2], a1[3]);
            aw[ks] = p.v;
        }

        f32x4 acc[2] = {};
        #pragma unroll
        for (int ks = 0; ks < 8; ++ks)
            #pragma unroll
            for (int mf = 0; mf < 2; ++mf)
                acc[mf] = __builtin_amdgcn_mfma_f32_16x16x32_bf16(
                    aw[ks], bh[mf * 8 + ks], acc[mf], 0, 0, 0);

        // D[n][m]: col=l15 -> m, rows lq*4+reg -> n (4 consecutive)
        #pragma unroll
        for (int mf = 0; mf < 2; ++mf) {
            const int m = mw + mf * 16 + l15;
            f32x4 o = acc[mf] + bv;
            *reinterpret_cast<f32x4*>(
                out + (size_t)m * NCLS + n0 + s * 16 + lq * 4) = o;
        }
    }
}

// ---------------------------------------------------------------------------
extern "C" void kernel_launch(void* const* d_in, const int* in_sizes, int n_in,
                              void* d_out, int out_size, void* d_ws, size_t ws_size,
                              hipStream_t stream) {
    const int*   X       = (const int*)  d_in[0];
    const float* C_table = (const float*)d_in[1];
    const float* U_i     = (const float*)d_in[2];
    const float* b_i     = (const float*)d_in[4];
    const float* U_c     = (const float*)d_in[8];
    const float* b_c     = (const float*)d_in[10];
    const float* U_o     = (const float*)d_in[11];
    const float* b_o     = (const float*)d_in[13];
    const float* W_w     = (const float*)d_in[26];
    const float* b_out   = (const float*)d_in[27];
    float* out = (float*)d_out;

    unsigned short* hws = (unsigned short*)d_ws;  // bf16 h_last, frag-major

    lstm_h_last<<<B_SZ / 2, 512, 0, stream>>>(X, C_table, U_i, b_i, U_c, b_c,
                                              U_o, b_o, hws);
    logits_gemm<<<NCLS / 64, 512, 0, stream>>>(hws, W_w, b_out, out);
}